// Round 1
// baseline (336.766 us; speedup 1.0000x reference)
//
#include <hip/hip_runtime.h>

#define NN 2048
#define BB 4
#define IN_F 128
#define OUT_F 64
#define NEG_INF -9000000000000000.0f
#define TI 8

// Kernel 1: Wh = h @ W  (per row: 64 outputs, one per thread),
// e_l[row] = Wh_row . a_l, e_r[row] = Wh_row . a_r (wave reduce).
__global__ __launch_bounds__(64) void wh_el_er_kernel(
    const float* __restrict__ h, const float* __restrict__ W,
    const float* __restrict__ a, float* __restrict__ Wh,
    float* __restrict__ el, float* __restrict__ er) {
  int row = blockIdx.x;           // b*NN + n
  int o = threadIdx.x;            // 0..63
  const float* hr = h + (size_t)row * IN_F;
  float wh = 0.f;
  #pragma unroll 8
  for (int f = 0; f < IN_F; ++f) wh += hr[f] * W[f * OUT_F + o];
  Wh[(size_t)row * OUT_F + o] = wh;
  float vl = wh * a[o];
  float vr = wh * a[OUT_F + o];
  #pragma unroll
  for (int d = 32; d > 0; d >>= 1) {
    vl += __shfl_down(vl, d);
    vr += __shfl_down(vr, d);
  }
  if (o == 0) { el[row] = vl; er[row] = vr; }
}

// Kernel 2: per block handles TI=8 rows of one batch.
// Phase 1: masked softmax per row (4 waves x 2 rows), attention written out,
//          normalized p kept in LDS.
// Phase 2: h_prime rows = p @ Wh with 8-way Wh reuse, LDS reduce, lrelu 0.01.
__global__ __launch_bounds__(256) void attn_kernel(
    const int* __restrict__ adj, const float* __restrict__ Wh,
    const float* __restrict__ el, const float* __restrict__ er,
    float* __restrict__ attn_out, float* __restrict__ hprime) {
  __shared__ float p[TI][NN];           // 64 KB
  __shared__ float red[4][TI][OUT_F];   // 8 KB

  int blk = blockIdx.x;                 // b * (NN/TI) + tile
  int b = blk / (NN / TI);
  int i0 = (blk % (NN / TI)) * TI;
  int tid = threadIdx.x;
  int wave = tid >> 6, lane = tid & 63;

  const float* erb = er + (size_t)b * NN;

  // ---- Phase 1: softmax rows (each wave owns 2 rows) ----
  for (int rr = 0; rr < 2; ++rr) {
    int r = wave * 2 + rr;
    int i = i0 + r;
    float eli = el[(size_t)b * NN + i];
    const int* arow = adj + ((size_t)b * NN + i) * NN;

    float mx = NEG_INF;
    for (int j = lane; j < NN; j += 64) {
      float e = eli + erb[j];
      e = e > 0.f ? e : 0.2f * e;        // leaky_relu 0.2
      float m = arow[j] > 0 ? e : NEG_INF;
      p[r][j] = m;
      mx = fmaxf(mx, m);
    }
    #pragma unroll
    for (int d = 32; d > 0; d >>= 1) mx = fmaxf(mx, __shfl_xor(mx, d));

    float s = 0.f;
    for (int j = lane; j < NN; j += 64) {
      float pe = __expf(p[r][j] - mx);   // all-masked row -> exp(0)=1 each
      p[r][j] = pe;
      s += pe;
    }
    #pragma unroll
    for (int d = 32; d > 0; d >>= 1) s += __shfl_xor(s, d);
    float inv = 1.f / s;

    float* orow = attn_out + ((size_t)b * NN + i) * NN;
    for (int j = lane; j < NN; j += 64) {
      float pn = p[r][j] * inv;
      p[r][j] = pn;
      orow[j] = pn;
    }
  }
  __syncthreads();

  // ---- Phase 2: h_prime = lrelu(p @ Wh, 0.01) ----
  int o = tid & 63, g = tid >> 6;       // 64 outputs x 4 j-groups
  const float* Whb = Wh + (size_t)b * NN * OUT_F;
  float acc[TI];
  #pragma unroll
  for (int r = 0; r < TI; ++r) acc[r] = 0.f;

  for (int j = g; j < NN; j += 4) {
    float w = Whb[(size_t)j * OUT_F + o];   // 256B coalesced per wave, L2-hot
    #pragma unroll
    for (int r = 0; r < TI; ++r) acc[r] += p[r][j] * w;  // LDS broadcast reads
  }
  #pragma unroll
  for (int r = 0; r < TI; ++r) red[g][r][o] = acc[r];
  __syncthreads();

  for (int idx = tid; idx < TI * OUT_F; idx += 256) {
    int r = idx >> 6, oo = idx & 63;
    float v = red[0][r][oo] + red[1][r][oo] + red[2][r][oo] + red[3][r][oo];
    v = v > 0.f ? v : 0.01f * v;          // leaky_relu 0.01
    hprime[((size_t)b * NN + i0 + r) * OUT_F + oo] = v;
  }
}

extern "C" void kernel_launch(void* const* d_in, const int* in_sizes, int n_in,
                              void* d_out, int out_size, void* d_ws, size_t ws_size,
                              hipStream_t stream) {
  const float* h  = (const float*)d_in[0];
  const int* adj  = (const int*)d_in[1];
  const float* W  = (const float*)d_in[2];
  const float* a  = (const float*)d_in[3];

  float* hprime   = (float*)d_out;                          // B*N*OUT_F
  float* attn_out = (float*)d_out + (size_t)BB * NN * OUT_F; // B*N*N

  // workspace: Wh (B*N*OUT_F f32), el (B*N), er (B*N)
  float* Wh = (float*)d_ws;
  float* el = Wh + (size_t)BB * NN * OUT_F;
  float* er = el + (size_t)BB * NN;

  hipLaunchKernelGGL(wh_el_er_kernel, dim3(BB * NN), dim3(64), 0, stream,
                     h, W, a, Wh, el, er);
  hipLaunchKernelGGL(attn_kernel, dim3(BB * (NN / TI)), dim3(256), 0, stream,
                     adj, Wh, el, er, attn_out, hprime);
}

// Round 2
// 84.229 us; speedup vs baseline: 3.9982x; 3.9982x over previous
//
#include <hip/hip_runtime.h>

#define NN 2048
#define BB 4
#define IN_F 128
#define OUT_F 64
#define NEG_INF -9000000000000000.0f
#define TI 8          // rows per block (= waves per block)
#define THREADS 512

// Kernel 1: Wh = h @ W (per row: 64 outputs, one per thread),
// e_l[row] = Wh_row . a_l, e_r[row] = Wh_row . a_r (wave reduce).
__global__ __launch_bounds__(64) void wh_el_er_kernel(
    const float* __restrict__ h, const float* __restrict__ W,
    const float* __restrict__ a, float* __restrict__ Wh,
    float* __restrict__ el, float* __restrict__ er) {
  int row = blockIdx.x;           // b*NN + n
  int o = threadIdx.x;            // 0..63
  const float* hr = h + (size_t)row * IN_F;
  float wh = 0.f;
  #pragma unroll 8
  for (int f = 0; f < IN_F; ++f) wh += hr[f] * W[f * OUT_F + o];
  Wh[(size_t)row * OUT_F + o] = wh;
  float vl = wh * a[o];
  float vr = wh * a[OUT_F + o];
  #pragma unroll
  for (int d = 32; d > 0; d >>= 1) {
    vl += __shfl_down(vl, d);
    vr += __shfl_down(vr, d);
  }
  if (o == 0) { el[row] = vl; er[row] = vr; }
}

// Kernel 2: one block = TI=8 rows of one batch, 8 waves.
// Phase 1: register-resident masked softmax per row (wave r owns row i0+r).
//          adj via int4, er via float4; 32 p-values live in VGPRs.
//          One float4 store pass to attention (global) and p (LDS).
// Phase 2: h_prime = lrelu(p @ Wh, 0.01); wave g streams Wh rows
//          [g*256, (g+1)*256), 8-row reuse of each Wh load via LDS broadcast.
__global__ __launch_bounds__(THREADS, 4) void attn_kernel(
    const int* __restrict__ adj, const float* __restrict__ Wh,
    const float* __restrict__ el, const float* __restrict__ er,
    float* __restrict__ attn_out, float* __restrict__ hprime) {
  __shared__ float p[TI][NN];   // 64 KB; first 16 KB reused as `red` later

  int blk = blockIdx.x;                 // b * (NN/TI) + tile
  int b = blk / (NN / TI);
  int i0 = (blk % (NN / TI)) * TI;
  int tid = threadIdx.x;
  int wave = tid >> 6, lane = tid & 63;

  // ---- Phase 1: softmax of row i = i0 + wave, fully in registers ----
  int i = i0 + wave;
  float eli = el[(size_t)b * NN + i];
  const int4* arow4 = (const int4*)(adj + ((size_t)(b * NN + i)) * NN);
  const float4* er4 = (const float4*)(er + (size_t)b * NN);

  float pv[8][4];
  float mx = NEG_INF;
  #pragma unroll 2
  for (int it = 0; it < 8; ++it) {
    int4 av = arow4[lane + 64 * it];     // j = (lane + 64*it)*4 + k
    float4 ev = er4[lane + 64 * it];
    float e0 = eli + ev.x; e0 = e0 > 0.f ? e0 : 0.2f * e0;
    float e1 = eli + ev.y; e1 = e1 > 0.f ? e1 : 0.2f * e1;
    float e2 = eli + ev.z; e2 = e2 > 0.f ? e2 : 0.2f * e2;
    float e3 = eli + ev.w; e3 = e3 > 0.f ? e3 : 0.2f * e3;
    pv[it][0] = av.x > 0 ? e0 : NEG_INF;
    pv[it][1] = av.y > 0 ? e1 : NEG_INF;
    pv[it][2] = av.z > 0 ? e2 : NEG_INF;
    pv[it][3] = av.w > 0 ? e3 : NEG_INF;
    mx = fmaxf(mx, fmaxf(fmaxf(pv[it][0], pv[it][1]), fmaxf(pv[it][2], pv[it][3])));
  }
  #pragma unroll
  for (int d = 32; d > 0; d >>= 1) mx = fmaxf(mx, __shfl_xor(mx, d));

  float s = 0.f;
  #pragma unroll
  for (int it = 0; it < 8; ++it) {
    #pragma unroll
    for (int k = 0; k < 4; ++k) {
      float pe = __expf(pv[it][k] - mx);   // all-masked row -> exp(0)=1 each
      pv[it][k] = pe;
      s += pe;
    }
  }
  #pragma unroll
  for (int d = 32; d > 0; d >>= 1) s += __shfl_xor(s, d);
  float inv = 1.f / s;

  float4* orow4 = (float4*)(attn_out + ((size_t)(b * NN + i)) * NN);
  float4* prow4 = (float4*)(&p[wave][0]);
  #pragma unroll 2
  for (int it = 0; it < 8; ++it) {
    float4 v;
    v.x = pv[it][0] * inv; v.y = pv[it][1] * inv;
    v.z = pv[it][2] * inv; v.w = pv[it][3] * inv;
    orow4[lane + 64 * it] = v;    // attention out (coalesced 1KB/wave)
    prow4[lane + 64 * it] = v;    // LDS, conflict-free contiguous b128
  }
  __syncthreads();

  // ---- Phase 2: h_prime = lrelu(p @ Wh, 0.01) ----
  const float* Whb = Wh + (size_t)b * NN * OUT_F;
  int g = wave, o = lane;
  float acc[TI];
  #pragma unroll
  for (int r = 0; r < TI; ++r) acc[r] = 0.f;

  int jbase = g * (NN / TI);
  #pragma unroll 4
  for (int it = 0; it < NN / TI; ++it) {
    int j = jbase + it;
    float w = Whb[(size_t)j * OUT_F + o];  // 256B coalesced, L2-hot
    #pragma unroll
    for (int r = 0; r < TI; ++r) acc[r] += p[r][j] * w;  // LDS broadcasts
  }
  __syncthreads();

  // reuse first 16 KB of p as red[8 groups][8 rows][64]
  float* red = (float*)p;
  #pragma unroll
  for (int r = 0; r < TI; ++r) red[(g * TI + r) * OUT_F + o] = acc[r];
  __syncthreads();

  {
    int r = wave, oo = lane;   // 512 threads = 8 rows x 64 outputs
    float v = 0.f;
    #pragma unroll
    for (int g2 = 0; g2 < TI; ++g2) v += red[(g2 * TI + r) * OUT_F + oo];
    v = v > 0.f ? v : 0.01f * v;          // leaky_relu 0.01
    hprime[((size_t)(b * NN + i0 + r)) * OUT_F + oo] = v;
  }
}

extern "C" void kernel_launch(void* const* d_in, const int* in_sizes, int n_in,
                              void* d_out, int out_size, void* d_ws, size_t ws_size,
                              hipStream_t stream) {
  const float* h  = (const float*)d_in[0];
  const int* adj  = (const int*)d_in[1];
  const float* W  = (const float*)d_in[2];
  const float* a  = (const float*)d_in[3];

  float* hprime   = (float*)d_out;                           // B*N*OUT_F
  float* attn_out = (float*)d_out + (size_t)BB * NN * OUT_F; // B*N*N

  // workspace: Wh (B*N*OUT_F f32), el (B*N), er (B*N)
  float* Wh = (float*)d_ws;
  float* el = Wh + (size_t)BB * NN * OUT_F;
  float* er = el + (size_t)BB * NN;

  hipLaunchKernelGGL(wh_el_er_kernel, dim3(BB * NN), dim3(64), 0, stream,
                     h, W, a, Wh, el, er);
  hipLaunchKernelGGL(attn_kernel, dim3(BB * (NN / TI)), dim3(THREADS), 0, stream,
                     adj, Wh, el, er, attn_out, hprime);
}

// Round 3
// 55.316 us; speedup vs baseline: 6.0880x; 1.5227x over previous
//
#include <hip/hip_runtime.h>

#define NN 2048
#define BB 4
#define IN_F 128
#define OUT_F 64
#define NEG_INF -9000000000000000.0f

typedef __attribute__((ext_vector_type(8))) short short8;
typedef __attribute__((ext_vector_type(4))) float f32x4;

__device__ __forceinline__ ushort f2bf(float f) {
  uint u = __float_as_uint(f);
  uint r = (u + 0x7fffu + ((u >> 16) & 1u)) >> 16;   // RNE, finite values
  return (ushort)r;
}

// Kernel 1: per row j: wh[o] = h[j] . W[:,o] (f32), write Whbf (bf16, row-major),
// el[j] = wh . a_l, er[j] = wh . a_r (wave reduce, f32).
__global__ __launch_bounds__(64) void wh_el_er_kernel(
    const float* __restrict__ h, const float* __restrict__ W,
    const float* __restrict__ a, ushort* __restrict__ Whbf,
    float* __restrict__ el, float* __restrict__ er) {
  int row = blockIdx.x;           // b*NN + n
  int o = threadIdx.x;            // 0..63
  const float* hr = h + (size_t)row * IN_F;
  float wh = 0.f;
  #pragma unroll 8
  for (int f = 0; f < IN_F; ++f) wh += hr[f] * W[f * OUT_F + o];
  Whbf[(size_t)row * OUT_F + o] = f2bf(wh);
  float vl = wh * a[o];
  float vr = wh * a[OUT_F + o];
  #pragma unroll
  for (int d = 32; d > 0; d >>= 1) {
    vl += __shfl_down(vl, d);
    vr += __shfl_down(vr, d);
  }
  if (o == 0) { el[row] = vl; er[row] = vr; }
}

// Kernel 1b: WhbfT[b][o][j] = Whbf[b][j][o] (bf16 transpose, per-batch 64x2048).
__global__ __launch_bounds__(256) void transpose_kernel(
    const ushort* __restrict__ Whbf, ushort* __restrict__ WhbfT) {
  __shared__ uint tile[64][65];
  int b = blockIdx.x >> 5;          // /32
  int j0 = (blockIdx.x & 31) << 6;  // *64
  int t = threadIdx.x;
  int o = t & 63, jg = t >> 6;      // 4 j-groups of 16
  #pragma unroll
  for (int m = 0; m < 16; ++m) {
    int jj = jg * 16 + m;
    tile[jj][o] = (uint)Whbf[((size_t)(b * NN + j0 + jj)) * OUT_F + o];
  }
  __syncthreads();
  int oo = t >> 2, grp = t & 3;     // 64 o x 4 chunks of 16 j
  uint out[8];
  #pragma unroll
  for (int m = 0; m < 16; m += 2) {
    uint u0 = tile[grp * 16 + m][oo];
    uint u1 = tile[grp * 16 + m + 1][oo];
    out[m >> 1] = u0 | (u1 << 16);
  }
  uint4* dst = (uint4*)(WhbfT + ((size_t)(b * OUT_F + oo)) * NN + j0 + grp * 16);
  dst[0] = *(uint4*)&out[0];
  dst[1] = *(uint4*)&out[4];
}

// Kernel 2: block = 16 rows of one batch, 512 threads (8 waves).
// Phase 1: wave w -> rows 2w, 2w+1: register softmax; write attention (f32,
//          global) and p (bf16, XOR-swizzled LDS).
// Phase 2: h_prime[16][64] = p @ Wh via mfma_f32_16x16x32_bf16.
//          wave = (ntile = w>>1, khalf = w&1); A-frag: 1x ds_read_b128 from
//          swizzled p; B-frag: 1x dwordx4 from WhbfT (8 contiguous k per lane).
//          Cross-khalf reduce in LDS, lrelu 0.01, store.
__global__ __launch_bounds__(512, 4) void attn_kernel(
    const int* __restrict__ adj, const ushort* __restrict__ WhbfT,
    const float* __restrict__ el, const float* __restrict__ er,
    float* __restrict__ attn_out, float* __restrict__ hprime) {
  __shared__ __align__(16) char pbuf[16 * 4096];  // p bf16 [16][2048], swizzled
  __shared__ float red[4][16][16];                // 4 KB cross-khalf reduce

  int blk = blockIdx.x;
  int b = blk >> 7;             // /128
  int i0 = (blk & 127) << 4;    // *16
  int tid = threadIdx.x;
  int wave = tid >> 6, lane = tid & 63;

  const float4* er4 = (const float4*)(er + (size_t)b * NN);

  // ---- Phase 1: masked softmax, 2 rows per wave ----
  for (int rr = 0; rr < 2; ++rr) {
    int r = wave * 2 + rr;
    int i = i0 + r;
    float eli = el[(size_t)b * NN + i];
    const int4* arow4 = (const int4*)(adj + ((size_t)(b * NN + i)) * NN);

    float pv[8][4];
    float mx = NEG_INF;
    #pragma unroll
    for (int it = 0; it < 8; ++it) {
      int4 av = arow4[lane + 64 * it];
      float4 ev = er4[lane + 64 * it];
      float e0 = eli + ev.x; e0 = e0 > 0.f ? e0 : 0.2f * e0;
      float e1 = eli + ev.y; e1 = e1 > 0.f ? e1 : 0.2f * e1;
      float e2 = eli + ev.z; e2 = e2 > 0.f ? e2 : 0.2f * e2;
      float e3 = eli + ev.w; e3 = e3 > 0.f ? e3 : 0.2f * e3;
      pv[it][0] = av.x > 0 ? e0 : NEG_INF;
      pv[it][1] = av.y > 0 ? e1 : NEG_INF;
      pv[it][2] = av.z > 0 ? e2 : NEG_INF;
      pv[it][3] = av.w > 0 ? e3 : NEG_INF;
      mx = fmaxf(mx, fmaxf(fmaxf(pv[it][0], pv[it][1]), fmaxf(pv[it][2], pv[it][3])));
    }
    #pragma unroll
    for (int d = 32; d > 0; d >>= 1) mx = fmaxf(mx, __shfl_xor(mx, d));

    float s = 0.f;
    #pragma unroll
    for (int it = 0; it < 8; ++it) {
      #pragma unroll
      for (int k = 0; k < 4; ++k) {
        float pe = __expf(pv[it][k] - mx);
        pv[it][k] = pe;
        s += pe;
      }
    }
    #pragma unroll
    for (int d = 32; d > 0; d >>= 1) s += __shfl_xor(s, d);
    float inv = 1.f / s;

    float4* orow4 = (float4*)(attn_out + ((size_t)(b * NN + i)) * NN);
    char* prow = pbuf + r * 4096;
    int sw = (r & 7) << 4;
    #pragma unroll
    for (int it = 0; it < 8; ++it) {
      float4 v;
      v.x = pv[it][0] * inv; v.y = pv[it][1] * inv;
      v.z = pv[it][2] * inv; v.w = pv[it][3] * inv;
      orow4[lane + 64 * it] = v;                       // attention f32 out
      uint lo = (uint)f2bf(v.x) | ((uint)f2bf(v.y) << 16);
      uint hi = (uint)f2bf(v.z) | ((uint)f2bf(v.w) << 16);
      uint2 w2; w2.x = lo; w2.y = hi;
      *(uint2*)(prow + (((lane + 64 * it) * 8) ^ sw)) = w2;  // swizzled bf16 p
    }
  }
  __syncthreads();

  // ---- Phase 2: MFMA p @ Wh ----
  int ntile = wave >> 1, khalf = wave & 1;
  int o0 = ntile * 16;
  int lo16 = lane & 15, hi4 = lane >> 4;

  const char* prow = pbuf + lo16 * 4096;
  int sw = (lo16 & 7) << 4;
  const ushort* brow = WhbfT + ((size_t)(b * OUT_F + o0 + lo16)) * NN;

  f32x4 acc = {0.f, 0.f, 0.f, 0.f};
  #pragma unroll 4
  for (int kk = 0; kk < 32; ++kk) {
    int kbase = khalf * 1024 + kk * 32 + hi4 * 8;
    short8 afrag = *(const short8*)(prow + ((kbase * 2) ^ sw));
    short8 bfrag = *(const short8*)(brow + kbase);
    acc = __builtin_amdgcn_mfma_f32_16x16x32_bf16(afrag, bfrag, acc, 0, 0, 0);
  }
  __syncthreads();

  if (khalf == 1) {
    #pragma unroll
    for (int q = 0; q < 4; ++q) red[ntile][hi4 * 4 + q][lo16] = acc[q];
  }
  __syncthreads();
  if (khalf == 0) {
    #pragma unroll
    for (int q = 0; q < 4; ++q) {
      int crow = hi4 * 4 + q;
      float v = acc[q] + red[ntile][crow][lo16];
      v = v > 0.f ? v : 0.01f * v;                     // leaky_relu 0.01
      hprime[((size_t)(b * NN + i0 + crow)) * OUT_F + o0 + lo16] = v;
    }
  }
}

extern "C" void kernel_launch(void* const* d_in, const int* in_sizes, int n_in,
                              void* d_out, int out_size, void* d_ws, size_t ws_size,
                              hipStream_t stream) {
  const float* h  = (const float*)d_in[0];
  const int* adj  = (const int*)d_in[1];
  const float* W  = (const float*)d_in[2];
  const float* a  = (const float*)d_in[3];

  float* hprime   = (float*)d_out;                           // B*N*OUT_F
  float* attn_out = (float*)d_out + (size_t)BB * NN * OUT_F; // B*N*N

  // workspace: Whbf bf16 [B*N*64], WhbfT bf16 [B*64*N], el f32, er f32 (~2.1 MB)
  ushort* Whbf  = (ushort*)d_ws;
  ushort* WhbfT = Whbf + (size_t)BB * NN * OUT_F;
  float* el = (float*)(WhbfT + (size_t)BB * OUT_F * NN);
  float* er = el + (size_t)BB * NN;

  hipLaunchKernelGGL(wh_el_er_kernel, dim3(BB * NN), dim3(64), 0, stream,
                     h, W, a, Whbf, el, er);
  hipLaunchKernelGGL(transpose_kernel, dim3(BB * (NN / 64)), dim3(256), 0, stream,
                     Whbf, WhbfT);
  hipLaunchKernelGGL(attn_kernel, dim3(BB * (NN / 16)), dim3(512), 0, stream,
                     adj, WhbfT, el, er, attn_out, hprime);
}